// Round 1
// baseline (150.854 us; speedup 1.0000x reference)
//
#include <hip/hip_runtime.h>

// CosinePrediction: out[e] = dot(u,v) / (max(||u||,eps) * max(||v||,eps))
// u = h_user[src_idx[e]], v = h_item[dst_idx[e]], D=64.
// Fused: norms computed on the gathered rows (algebraically equal to
// normalizing first). 16 lanes per edge, one float4 per lane -> the 16-lane
// group reads the whole 256B row contiguously. 4 edges/wave, 64 edges/block.

#define D 64
#define LANES_PER_EDGE 16
#define EPS 1e-12f

__global__ __launch_bounds__(256) void cos_edge_kernel(
    const float* __restrict__ h_user,
    const float* __restrict__ h_item,
    const int* __restrict__ src_idx,
    const int* __restrict__ dst_idx,
    float* __restrict__ out,
    int E)
{
    int tid  = blockIdx.x * blockDim.x + threadIdx.x;
    int edge = tid >> 4;        // 16 lanes per edge
    int lane = tid & 15;
    if (edge >= E) return;

    int s = src_idx[edge];
    int t = dst_idx[edge];

    const float4 u = *(const float4*)(h_user + (size_t)s * D + lane * 4);
    const float4 v = *(const float4*)(h_item + (size_t)t * D + lane * 4);

    float dot = u.x * v.x + u.y * v.y + u.z * v.z + u.w * v.w;
    float uu  = u.x * u.x + u.y * u.y + u.z * u.z + u.w * u.w;
    float vv  = v.x * v.x + v.y * v.y + v.z * v.z + v.w * v.w;

    // reduce across the 16 lanes of this edge
    #pragma unroll
    for (int off = 8; off >= 1; off >>= 1) {
        dot += __shfl_down(dot, off, LANES_PER_EDGE);
        uu  += __shfl_down(uu,  off, LANES_PER_EDGE);
        vv  += __shfl_down(vv,  off, LANES_PER_EDGE);
    }

    if (lane == 0) {
        float nu = fmaxf(sqrtf(uu), EPS);
        float nv = fmaxf(sqrtf(vv), EPS);
        out[edge] = dot / (nu * nv);
    }
}

extern "C" void kernel_launch(void* const* d_in, const int* in_sizes, int n_in,
                              void* d_out, int out_size, void* d_ws, size_t ws_size,
                              hipStream_t stream) {
    const float* h_user = (const float*)d_in[0];
    const float* h_item = (const float*)d_in[1];
    const int*   src    = (const int*)d_in[2];
    const int*   dst    = (const int*)d_in[3];
    float*       out    = (float*)d_out;

    int E = in_sizes[2];   // number of edges

    const int threads = 256;
    // 16 lanes per edge -> E*16 total threads (16e6, fits int32)
    int blocks = (E * LANES_PER_EDGE + threads - 1) / threads;
    cos_edge_kernel<<<blocks, threads, 0, stream>>>(h_user, h_item, src, dst, out, E);
}

// Round 2
// 130.145 us; speedup vs baseline: 1.1591x; 1.1591x over previous
//
#include <hip/hip_runtime.h>
#include <hip/hip_fp16.h>

// CosinePrediction, two-pass:
//  Pass 1: L2-normalize h_user/h_item rows (fp32 math) -> fp16 tables in d_ws.
//          Halves the gather footprint (51.2 -> 25.6 MB) and bytes/row
//          (256 -> 128 B), which is what the L2-miss-bound edge gather pays.
//  Pass 2: per-edge gather + dot on fp16 rows. 8 lanes/edge, one float4
//          (8 halves) per lane per row -> 128 B row read contiguously by the
//          8-lane group. Only the dot is reduced (3 shuffle steps).
// Fallback: fused fp32 single-pass kernel if ws_size is too small.

#define D 64
#define EPS 1e-12f

// ---------------- Pass 1: normalize fp32 row -> fp16 row ----------------
// 16 lanes per row, one float4 per lane. 4 rows per wave, 16 rows per block.
__global__ __launch_bounds__(256) void normalize_f16_kernel(
    const float* __restrict__ src, __half* __restrict__ dst, int nrows)
{
    int tid  = blockIdx.x * blockDim.x + threadIdx.x;
    int row  = tid >> 4;
    int lane = tid & 15;
    if (row >= nrows) return;

    const float4 u = *(const float4*)(src + (size_t)row * D + lane * 4);
    float ss = u.x * u.x + u.y * u.y + u.z * u.z + u.w * u.w;
    #pragma unroll
    for (int off = 8; off >= 1; off >>= 1)
        ss += __shfl_down(ss, off, 16);
    ss = __shfl(ss, 0, 16);                      // broadcast sum within group
    float inv = 1.0f / fmaxf(sqrtf(ss), EPS);

    __half2* d = (__half2*)(dst + (size_t)row * D + lane * 4);
    d[0] = __floats2half2_rn(u.x * inv, u.y * inv);
    d[1] = __floats2half2_rn(u.z * inv, u.w * inv);
}

// ---------------- Pass 2: edge gather + dot (fp16 rows) ----------------
// 8 lanes per edge, one float4 (= 8 halves) per lane per row.
__global__ __launch_bounds__(256) void cos_edge_f16_kernel(
    const __half* __restrict__ nu,
    const __half* __restrict__ ni,
    const int* __restrict__ src_idx,
    const int* __restrict__ dst_idx,
    float* __restrict__ out,
    int E)
{
    int tid  = blockIdx.x * blockDim.x + threadIdx.x;
    int edge = tid >> 3;
    int lane = tid & 7;
    if (edge >= E) return;

    int s = src_idx[edge];
    int t = dst_idx[edge];

    const float4 uraw = *(const float4*)(nu + (size_t)s * D + lane * 8);
    const float4 vraw = *(const float4*)(ni + (size_t)t * D + lane * 8);
    const __half2* uh = reinterpret_cast<const __half2*>(&uraw);
    const __half2* vh = reinterpret_cast<const __half2*>(&vraw);

    float dot = 0.0f;
    #pragma unroll
    for (int i = 0; i < 4; ++i) {
        float2 a = __half22float2(uh[i]);
        float2 b = __half22float2(vh[i]);
        dot = fmaf(a.x, b.x, dot);
        dot = fmaf(a.y, b.y, dot);
    }

    #pragma unroll
    for (int off = 4; off >= 1; off >>= 1)
        dot += __shfl_down(dot, off, 8);

    if (lane == 0) out[edge] = dot;
}

// ---------------- Fallback: fused fp32 single pass ----------------
__global__ __launch_bounds__(256) void cos_edge_f32_kernel(
    const float* __restrict__ h_user,
    const float* __restrict__ h_item,
    const int* __restrict__ src_idx,
    const int* __restrict__ dst_idx,
    float* __restrict__ out,
    int E)
{
    int tid  = blockIdx.x * blockDim.x + threadIdx.x;
    int edge = tid >> 4;
    int lane = tid & 15;
    if (edge >= E) return;

    int s = src_idx[edge];
    int t = dst_idx[edge];

    const float4 u = *(const float4*)(h_user + (size_t)s * D + lane * 4);
    const float4 v = *(const float4*)(h_item + (size_t)t * D + lane * 4);

    float dot = u.x * v.x + u.y * v.y + u.z * v.z + u.w * v.w;
    float uu  = u.x * u.x + u.y * u.y + u.z * u.z + u.w * u.w;
    float vv  = v.x * v.x + v.y * v.y + v.z * v.z + v.w * v.w;

    #pragma unroll
    for (int off = 8; off >= 1; off >>= 1) {
        dot += __shfl_down(dot, off, 16);
        uu  += __shfl_down(uu,  off, 16);
        vv  += __shfl_down(vv,  off, 16);
    }

    if (lane == 0) {
        float nup = fmaxf(sqrtf(uu), EPS);
        float nvp = fmaxf(sqrtf(vv), EPS);
        out[edge] = dot / (nup * nvp);
    }
}

extern "C" void kernel_launch(void* const* d_in, const int* in_sizes, int n_in,
                              void* d_out, int out_size, void* d_ws, size_t ws_size,
                              hipStream_t stream) {
    const float* h_user = (const float*)d_in[0];
    const float* h_item = (const float*)d_in[1];
    const int*   src    = (const int*)d_in[2];
    const int*   dst    = (const int*)d_in[3];
    float*       out    = (float*)d_out;

    const int NU = in_sizes[0] / D;
    const int NI = in_sizes[1] / D;
    const int E  = in_sizes[2];

    const size_t need = ((size_t)NU + (size_t)NI) * D * sizeof(__half);

    if (ws_size >= need) {
        __half* nu = (__half*)d_ws;
        __half* ni = nu + (size_t)NU * D;

        // Pass 1: normalize both tables (16 lanes/row).
        {
            int threads = 256;
            int blocks_u = (NU * 16 + threads - 1) / threads;
            int blocks_i = (NI * 16 + threads - 1) / threads;
            normalize_f16_kernel<<<blocks_u, threads, 0, stream>>>(h_user, nu, NU);
            normalize_f16_kernel<<<blocks_i, threads, 0, stream>>>(h_item, ni, NI);
        }
        // Pass 2: edge dot (8 lanes/edge).
        {
            int threads = 256;
            int blocks = (E * 8 + threads - 1) / threads;
            cos_edge_f16_kernel<<<blocks, threads, 0, stream>>>(nu, ni, src, dst, out, E);
        }
    } else {
        int threads = 256;
        int blocks = (E * 16 + threads - 1) / threads;
        cos_edge_f32_kernel<<<blocks, threads, 0, stream>>>(h_user, h_item, src, dst, out, E);
    }
}

// Round 3
// 124.899 us; speedup vs baseline: 1.2078x; 1.0420x over previous
//
#include <hip/hip_runtime.h>

// CosinePrediction, int8 two-pass:
//  Pass 1 (one dispatch): L2-normalize rows of both tables (fp32 math),
//          quantize to int8 with per-row scale s = max|y|/127 -> d_ws.
//          Row shrinks to 64 B (1 cache line), footprint 12.8 MB.
//  Pass 2: per-edge gather + int8 dot via v_dot4_i32_i8, out = s_u*s_v*idot.
//          4 lanes/edge, one int4 (16 int8) per lane -> 64 B row read as one
//          contiguous cache line by the 4-lane group. 16 edges/wave.
// Fallback: fused fp32 single-pass kernel if ws_size is too small.

#define D 64
#define EPS 1e-12f

// ---------------- Pass 1: normalize + int8-quantize both tables ----------------
// 16 lanes per row, one float4 per lane. Rows [0,NU) -> user, [NU,NU+NI) -> item.
__global__ __launch_bounds__(256) void quantize_both_kernel(
    const float* __restrict__ h_user, const float* __restrict__ h_item,
    char4* __restrict__ qu, char4* __restrict__ qi,
    float* __restrict__ su, float* __restrict__ si,
    int NU, int NTOT)
{
    int tid  = blockIdx.x * blockDim.x + threadIdx.x;
    int row  = tid >> 4;
    int lane = tid & 15;
    if (row >= NTOT) return;

    const float* src; char4* dst; float* sc; int r;
    if (row < NU) { src = h_user; dst = qu; sc = su; r = row; }
    else          { src = h_item; dst = qi; sc = si; r = row - NU; }

    const float4 u = *(const float4*)(src + (size_t)r * D + lane * 4);
    float ss = u.x * u.x + u.y * u.y + u.z * u.z + u.w * u.w;
    float ma = fmaxf(fmaxf(fabsf(u.x), fabsf(u.y)),
                     fmaxf(fabsf(u.z), fabsf(u.w)));
    #pragma unroll
    for (int m = 8; m >= 1; m >>= 1) {
        ss += __shfl_xor(ss, m, 16);
        ma  = fmaxf(ma, __shfl_xor(ma, m, 16));
    }
    float inv = 1.0f / fmaxf(sqrtf(ss), EPS);   // 1/||x||
    // q_i = rint(127 * (x_i*inv) / (ma*inv)) = rint(x_i * 127/ma)
    float f = (ma > 0.0f) ? 127.0f / ma : 0.0f;
    float s = ma * inv * (1.0f / 127.0f);       // per-row dequant scale

    char4 q;
    q.x = (signed char)__float2int_rn(u.x * f);
    q.y = (signed char)__float2int_rn(u.y * f);
    q.z = (signed char)__float2int_rn(u.z * f);
    q.w = (signed char)__float2int_rn(u.w * f);
    dst[(size_t)r * 16 + lane] = q;
    if (lane == 0) sc[r] = s;
}

// ---------------- Pass 2: edge gather + int8 dot ----------------
// 4 lanes per edge, one int4 (16 bytes = 16 int8) per lane per row.
__global__ __launch_bounds__(256) void cos_edge_i8_kernel(
    const int4* __restrict__ qu, const int4* __restrict__ qi,
    const float* __restrict__ su, const float* __restrict__ si,
    const int* __restrict__ src_idx, const int* __restrict__ dst_idx,
    float* __restrict__ out, int E)
{
    int tid  = blockIdx.x * blockDim.x + threadIdx.x;
    int edge = tid >> 2;
    int lane = tid & 3;
    if (edge >= E) return;

    int s = src_idx[edge];
    int t = dst_idx[edge];

    const int4 a = qu[(size_t)s * 4 + lane];
    const int4 b = qi[(size_t)t * 4 + lane];

    int acc = 0;
#if __has_builtin(__builtin_amdgcn_sdot4)
    acc = __builtin_amdgcn_sdot4(a.x, b.x, acc, false);
    acc = __builtin_amdgcn_sdot4(a.y, b.y, acc, false);
    acc = __builtin_amdgcn_sdot4(a.z, b.z, acc, false);
    acc = __builtin_amdgcn_sdot4(a.w, b.w, acc, false);
#else
    {
        const signed char* pa = (const signed char*)&a;
        const signed char* pb = (const signed char*)&b;
        #pragma unroll
        for (int i = 0; i < 16; ++i) acc += (int)pa[i] * (int)pb[i];
    }
#endif

    acc += __shfl_xor(acc, 1, 4);
    acc += __shfl_xor(acc, 2, 4);

    if (lane == 0) out[edge] = su[s] * si[t] * (float)acc;
}

// ---------------- Fallback: fused fp32 single pass ----------------
__global__ __launch_bounds__(256) void cos_edge_f32_kernel(
    const float* __restrict__ h_user,
    const float* __restrict__ h_item,
    const int* __restrict__ src_idx,
    const int* __restrict__ dst_idx,
    float* __restrict__ out,
    int E)
{
    int tid  = blockIdx.x * blockDim.x + threadIdx.x;
    int edge = tid >> 4;
    int lane = tid & 15;
    if (edge >= E) return;

    int s = src_idx[edge];
    int t = dst_idx[edge];

    const float4 u = *(const float4*)(h_user + (size_t)s * D + lane * 4);
    const float4 v = *(const float4*)(h_item + (size_t)t * D + lane * 4);

    float dot = u.x * v.x + u.y * v.y + u.z * v.z + u.w * v.w;
    float uu  = u.x * u.x + u.y * u.y + u.z * u.z + u.w * u.w;
    float vv  = v.x * v.x + v.y * v.y + v.z * v.z + v.w * v.w;

    #pragma unroll
    for (int off = 8; off >= 1; off >>= 1) {
        dot += __shfl_down(dot, off, 16);
        uu  += __shfl_down(uu,  off, 16);
        vv  += __shfl_down(vv,  off, 16);
    }

    if (lane == 0) {
        float nup = fmaxf(sqrtf(uu), EPS);
        float nvp = fmaxf(sqrtf(vv), EPS);
        out[edge] = dot / (nup * nvp);
    }
}

extern "C" void kernel_launch(void* const* d_in, const int* in_sizes, int n_in,
                              void* d_out, int out_size, void* d_ws, size_t ws_size,
                              hipStream_t stream) {
    const float* h_user = (const float*)d_in[0];
    const float* h_item = (const float*)d_in[1];
    const int*   src    = (const int*)d_in[2];
    const int*   dst    = (const int*)d_in[3];
    float*       out    = (float*)d_out;

    const int NU = in_sizes[0] / D;
    const int NI = in_sizes[1] / D;
    const int E  = in_sizes[2];

    // ws layout: qu[NU*64 B] | qi[NI*64 B] | su[NU f32] | si[NI f32]
    const size_t qu_bytes = (size_t)NU * D;
    const size_t qi_bytes = (size_t)NI * D;
    const size_t need = qu_bytes + qi_bytes
                      + ((size_t)NU + (size_t)NI) * sizeof(float);

    if (ws_size >= need) {
        char*  base = (char*)d_ws;
        char4* qu = (char4*)base;
        char4* qi = (char4*)(base + qu_bytes);
        float* su = (float*)(base + qu_bytes + qi_bytes);
        float* si = su + NU;

        int threads = 256;
        int NTOT = NU + NI;
        int blocks1 = (NTOT * 16 + threads - 1) / threads;
        quantize_both_kernel<<<blocks1, threads, 0, stream>>>(
            h_user, h_item, qu, qi, su, si, NU, NTOT);

        int blocks2 = (E * 4 + threads - 1) / threads;
        cos_edge_i8_kernel<<<blocks2, threads, 0, stream>>>(
            (const int4*)qu, (const int4*)qi, su, si, src, dst, out, E);
    } else {
        int threads = 256;
        int blocks = (E * 16 + threads - 1) / threads;
        cos_edge_f32_kernel<<<blocks, threads, 0, stream>>>(
            h_user, h_item, src, dst, out, E);
    }
}